// Round 12
// baseline (259.645 us; speedup 1.0000x reference)
//
#include <hip/hip_runtime.h>
#include <hip/hip_bf16.h>
#include <stdint.h>

typedef __attribute__((ext_vector_type(8))) short bf16x8;
typedef __attribute__((ext_vector_type(4))) float f32x4;

#define DEVINL __device__ __forceinline__

// ---------------------------------------------------------------- helpers
DEVINL unsigned short f2bf(float f) {
  unsigned int u = __builtin_bit_cast(unsigned int, f);
  u += 0x7fffu + ((u >> 16) & 1u);   // RNE
  return (unsigned short)(u >> 16);
}

DEVINL unsigned int cvt_pk_bf16(float lo, float hi) {
  unsigned int r;
  asm("v_cvt_pk_bf16_f32 %0, %1, %2" : "=v"(r) : "v"(lo), "v"(hi));
  return r;
}

DEVINL void gload_lds16(const void* gptr, void* lptr) {
  __builtin_amdgcn_global_load_lds(
      (__attribute__((address_space(1))) void*)(uintptr_t)gptr,
      (__attribute__((address_space(3))) void*)(uint32_t)(uintptr_t)lptr,
      16, 0, 0);
}

// ---------------------------------------------------------------- fp32 -> bf16
__global__ __launch_bounds__(256) void cvt_bf16_kernel(const float* __restrict__ src,
                                                       unsigned short* __restrict__ dst,
                                                       int n) {
  int i = (blockIdx.x * 256 + threadIdx.x) * 4;
  if (i >= n) return;
  const float4 v = *reinterpret_cast<const float4*>(src + i);
  ushort4 o;
  o.x = f2bf(v.x); o.y = f2bf(v.y); o.z = f2bf(v.z); o.w = f2bf(v.w);
  *reinterpret_cast<ushort4*>(dst + i) = o;
}

// ---------------------------------------------------------------- fused QKV GEMM (unchanged)
__global__ __launch_bounds__(256) void qkv_gemm_kernel(
    const unsigned short* __restrict__ xbf,   // [4096][1024] bf16
    const unsigned short* __restrict__ wcat,  // [3072][1024] bf16
    const float* __restrict__ bq,
    const float* __restrict__ bk,
    const float* __restrict__ bv,
    float* __restrict__ out_k,                // [B,H,T,D] f32
    float* __restrict__ out_v,                // [B,H,T,D] f32
    unsigned short* __restrict__ qbf,         // [B,H,T,D] bf16
    unsigned short* __restrict__ kbf,         // [B,H,T,D] bf16
    unsigned short* __restrict__ vtr)         // [B,H,D,T] bf16
{
  __shared__ unsigned short As[128 * 32];
  __shared__ unsigned short Bs[128 * 32];
  const int t = threadIdx.x;
  const int l = t & 63;
  const int w = t >> 6;
  const int lr = l & 15, lg = l >> 4;
  const int wr = w >> 1, wc = w & 1;
  const int m0 = blockIdx.y * 128;
  const int n0 = blockIdx.x * 128;

  const int row0 = (t * 8) >> 5, col0 = (t * 8) & 31;
  const int row1 = ((256 + t) * 8) >> 5, col1 = ((256 + t) * 8) & 31;
  const unsigned short* aG0 = xbf + (m0 + row0) * 1024 + col0;
  const unsigned short* aG1 = xbf + (m0 + row1) * 1024 + col1;
  const unsigned short* bG0 = wcat + (n0 + row0) * 1024 + col0;
  const unsigned short* bG1 = wcat + (n0 + row1) * 1024 + col1;
  unsigned short* aL0 = As + t * 8;
  unsigned short* aL1 = As + (256 + t) * 8;
  unsigned short* bL0 = Bs + t * 8;
  unsigned short* bL1 = Bs + (256 + t) * 8;

  const int aOff = (wr * 64 + lr) * 32 + 8 * lg;
  const int bOff = (wc * 64 + lr) * 32 + 8 * lg;

  f32x4 acc[4][4];
  const f32x4 zf = {0.f, 0.f, 0.f, 0.f};
#pragma unroll
  for (int i = 0; i < 4; i++)
#pragma unroll
    for (int j = 0; j < 4; j++) acc[i][j] = zf;

  for (int kt = 0; kt < 1024; kt += 32) {
    gload_lds16(aG0 + kt, aL0);
    gload_lds16(aG1 + kt, aL1);
    gload_lds16(bG0 + kt, bL0);
    gload_lds16(bG1 + kt, bL1);
    __syncthreads();
    bf16x8 af[4], bfr[4];
#pragma unroll
    for (int mi = 0; mi < 4; mi++)
      af[mi] = *reinterpret_cast<const bf16x8*>(As + aOff + mi * 16 * 32);
#pragma unroll
    for (int ni = 0; ni < 4; ni++)
      bfr[ni] = *reinterpret_cast<const bf16x8*>(Bs + bOff + ni * 16 * 32);
#pragma unroll
    for (int mi = 0; mi < 4; mi++)
#pragma unroll
      for (int ni = 0; ni < 4; ni++)
        acc[mi][ni] = __builtin_amdgcn_mfma_f32_16x16x32_bf16(af[mi], bfr[ni], acc[mi][ni], 0, 0, 0);
    __syncthreads();
  }

  const int which = n0 >> 10;
  const float* bias = (which == 0) ? bq : (which == 1) ? bk : bv;
#pragma unroll
  for (int ni = 0; ni < 4; ni++) {
    const int n = n0 + wc * 64 + ni * 16 + lr;
    const int co = n & 1023;
    const float bb = bias[co];
    const int h = co >> 6, d = co & 63;
#pragma unroll
    for (int mi = 0; mi < 4; mi++) {
#pragma unroll
      for (int r = 0; r < 4; r++) {
        const int m = m0 + wr * 64 + mi * 16 + 4 * lg + r;
        const float val = acc[mi][ni][r] + bb;
        const int bb_ = m >> 11, tt = m & 2047;
        const int bh = bb_ * 16 + h;
        const int idx = (bh * 2048 + tt) * 64 + d;
        if (which == 0) {
          qbf[idx] = f2bf(val);
        } else if (which == 1) {
          out_k[idx] = val;
          kbf[idx] = f2bf(val);
        } else {
          out_v[idx] = val;
          vtr[(bh * 64 + d) * 2048 + tt] = f2bf(val);
        }
      }
    }
  }
}

// ---------------------------------------------------------------- flash attention v3
// v2 + KVBLK=128 (amortize softmax chain), base-2 softmax with folded scale,
// cvt_pk_bf16 asm pack, defer-rescale (skip acc rescale when max growth < 8).
// Swapped QK^T: lane owns q-row = qbase + (lane&15); 32 in-lane scores/block
// quadrant via 4*lg+r; full row across lanes lr, lr+16, lr+32, lr+48.
__global__ __launch_bounds__(512) void attn_kernel(
    const unsigned short* __restrict__ qbf,  // [BH][T][D] bf16
    const unsigned short* __restrict__ kbf,  // [BH][T][D] bf16
    const unsigned short* __restrict__ vtr,  // [BH][D][T] bf16
    float* __restrict__ y)                   // [B,T,C] f32
{
  __shared__ unsigned short pbuf[8][16 * 136];   // row stride 272B (16-aligned)
  const int w = threadIdx.x >> 6, l = threadIdx.x & 63;
  const int lr = l & 15, lg = l >> 4;

  // XCD-swizzle: xcd = blk&7 owns heads {4*xcd .. 4*xcd+3} -> K/V L2-resident
  const int blk = blockIdx.x;
  const int xcd = blk & 7, slot = blk >> 3;     // slot 0..63
  const int bh = xcd * 4 + (slot & 3);          // 0..31
  const int p = slot >> 2;                      // 0..15
  const int qt = (w < 4) ? p : (31 - p);
  const int qbase = qt * 64 + (w & 3) * 16;
  const int b = bh >> 4, h = bh & 15;

  const unsigned short* Q = qbf + bh * 2048 * 64;
  const unsigned short* K = kbf + bh * 2048 * 64;
  const unsigned short* V = vtr + bh * 64 * 2048;
  unsigned short* pb = pbuf[w];

  const int qrow = qbase + lr;                  // this lane's q row
  const bf16x8 qf0 = *reinterpret_cast<const bf16x8*>(Q + qrow * 64 + 8 * lg);
  const bf16x8 qf1 = *reinterpret_cast<const bf16x8*>(Q + qrow * 64 + 32 + 8 * lg);

  // base-2 domain: P = 2^(S*cs - m); cs = (1/8) * log2(e)
  const float cs = 0.125f * 1.4426950408889634f;
  const float THR = 8.0f * 1.4426950408889634f;  // defer threshold (e^8 in base-2)

  float mi = -1e30f, li = 0.f;
  f32x4 acc[4];
  const f32x4 zf = {0.f, 0.f, 0.f, 0.f};
#pragma unroll
  for (int dt = 0; dt < 4; dt++) acc[dt] = zf;

  const int nkv = qbase + 16;
  for (int kb = 0; kb < nkv; kb += 128) {
    // ---- QK^T swapped: S^T[key][q]; 8 key-subtiles of 16
    f32x4 s[8];
#pragma unroll
    for (int kt = 0; kt < 8; kt++) {
      const unsigned short* kr = K + (kb + kt * 16 + lr) * 64;
      const bf16x8 kf0 = *reinterpret_cast<const bf16x8*>(kr + 8 * lg);
      const bf16x8 kf1 = *reinterpret_cast<const bf16x8*>(kr + 32 + 8 * lg);
      f32x4 t = zf;
      t = __builtin_amdgcn_mfma_f32_16x16x32_bf16(kf0, qf0, t, 0, 0, 0);
      t = __builtin_amdgcn_mfma_f32_16x16x32_bf16(kf1, qf1, t, 0, 0, 0);
      s[kt] = t;
    }
    // ---- scale (base-2) + causal mask; key = kb + kt*16 + 4*lg + r
    float v[32];
#pragma unroll
    for (int kt = 0; kt < 8; kt++)
#pragma unroll
      for (int r = 0; r < 4; r++) {
        const int key = kb + kt * 16 + 4 * lg + r;
        const float val = s[kt][r] * cs;
        v[kt * 4 + r] = (key > qrow) ? -1e30f : val;
      }
    // ---- row max: in-lane tree (31) + 2 shfl
    float t16[16];
#pragma unroll
    for (int i = 0; i < 16; i++) t16[i] = fmaxf(v[2 * i], v[2 * i + 1]);
    float t8[8];
#pragma unroll
    for (int i = 0; i < 8; i++) t8[i] = fmaxf(t16[2 * i], t16[2 * i + 1]);
    float t4[4];
#pragma unroll
    for (int i = 0; i < 4; i++) t4[i] = fmaxf(t8[2 * i], t8[2 * i + 1]);
    float mr = fmaxf(fmaxf(t4[0], t4[1]), fmaxf(t4[2], t4[3]));
    mr = fmaxf(mr, __shfl_xor(mr, 16));
    mr = fmaxf(mr, __shfl_xor(mr, 32));
    // ---- defer-rescale: only rescale when some row's max grew past THR
    if (__any(mr > mi + THR)) {
      const float mnew = fmaxf(mi, mr);
      const float alpha = exp2f(mi - mnew);
      mi = mnew;
      li *= alpha;
#pragma unroll
      for (int dt = 0; dt < 4; dt++)
#pragma unroll
        for (int r = 0; r < 4; r++) acc[dt][r] *= alpha;
    }
    // ---- exp2 + row sum
#pragma unroll
    for (int i = 0; i < 32; i++) v[i] = exp2f(v[i] - mi);
    float u16[16];
#pragma unroll
    for (int i = 0; i < 16; i++) u16[i] = v[2 * i] + v[2 * i + 1];
    float u8[8];
#pragma unroll
    for (int i = 0; i < 8; i++) u8[i] = u16[2 * i] + u16[2 * i + 1];
    float u4[4];
#pragma unroll
    for (int i = 0; i < 4; i++) u4[i] = u8[2 * i] + u8[2 * i + 1];
    float sr = (u4[0] + u4[1]) + (u4[2] + u4[3]);
    sr += __shfl_xor(sr, 16);
    sr += __shfl_xor(sr, 32);
    li += sr;
    // ---- P^T -> LDS [q=lr][128 keys], stride 136 shorts; cvt_pk u32 writes
#pragma unroll
    for (int kt = 0; kt < 8; kt++)
#pragma unroll
      for (int i = 0; i < 2; i++) {
        const unsigned int pk = cvt_pk_bf16(v[kt * 4 + 2 * i], v[kt * 4 + 2 * i + 1]);
        *reinterpret_cast<unsigned int*>(pb + lr * 136 + kt * 16 + 4 * lg + 2 * i) = pk;
      }
    // same-wave LDS RAW: DS completes in order; compiler inserts lgkmcnt
    // ---- PV: y^T[d][q] += V^T[d][key] * P^T[key][q]; 4 chunks of K=32
#pragma unroll
    for (int kc = 0; kc < 4; kc++) {
      const bf16x8 pf = *reinterpret_cast<const bf16x8*>(pb + lr * 136 + kc * 32 + 8 * lg);
#pragma unroll
      for (int dt = 0; dt < 4; dt++) {
        const bf16x8 vf = *reinterpret_cast<const bf16x8*>(
            V + (dt * 16 + lr) * 2048 + kb + kc * 32 + 8 * lg);
        acc[dt] = __builtin_amdgcn_mfma_f32_16x16x32_bf16(vf, pf, acc[dt], 0, 0, 0);
      }
    }
  }

  // ---- epilogue: lane holds y[qrow][d], d = dt*16 + 4*lg + r (r contiguous)
  const float inv = 1.0f / li;
  float* yb = y + (b * 2048 + qrow) * 1024 + h * 64;
#pragma unroll
  for (int dt = 0; dt < 4; dt++) {
    float4 o;
    o.x = acc[dt][0] * inv; o.y = acc[dt][1] * inv;
    o.z = acc[dt][2] * inv; o.w = acc[dt][3] * inv;
    *reinterpret_cast<float4*>(yb + dt * 16 + 4 * lg) = o;
  }
}

// ---------------------------------------------------------------- launch
extern "C" void kernel_launch(void* const* d_in, const int* in_sizes, int n_in,
                              void* d_out, int out_size, void* d_ws, size_t ws_size,
                              hipStream_t stream) {
  const float* x  = (const float*)d_in[0];
  const float* Wq = (const float*)d_in[1];
  const float* bq = (const float*)d_in[2];
  const float* Wk = (const float*)d_in[3];
  const float* bk = (const float*)d_in[4];
  const float* Wv = (const float*)d_in[5];
  const float* bv = (const float*)d_in[6];

  float* y = (float*)d_out;                 // [B,T,C]      4,194,304
  float* out_k = y + 4194304;               // [B,H,T,D]    4,194,304
  float* out_v = y + 8388608;               // [B,H,T,D]    4,194,304

  char* wsb = (char*)d_ws;                  // 38 MB used
  unsigned short* xbf  = (unsigned short*)(wsb);                    // 8 MB [4096][1024]
  unsigned short* wcat = (unsigned short*)(wsb + (8u  << 20));      // 6 MB [3072][1024]
  unsigned short* qbf  = (unsigned short*)(wsb + (14u << 20));      // 8 MB [BH][T][D]
  unsigned short* kbf  = (unsigned short*)(wsb + (22u << 20));      // 8 MB [BH][T][D]
  unsigned short* vtr  = (unsigned short*)(wsb + (30u << 20));      // 8 MB [BH][D][T]

  cvt_bf16_kernel<<<4096, 256, 0, stream>>>(x, xbf, 4194304);
  cvt_bf16_kernel<<<1024, 256, 0, stream>>>(Wq, wcat, 1048576);
  cvt_bf16_kernel<<<1024, 256, 0, stream>>>(Wk, wcat + 1048576, 1048576);
  cvt_bf16_kernel<<<1024, 256, 0, stream>>>(Wv, wcat + 2097152, 1048576);

  qkv_gemm_kernel<<<dim3(24, 32), 256, 0, stream>>>(xbf, wcat, bq, bk, bv,
                                                    out_k, out_v, qbf, kbf, vtr);

  attn_kernel<<<512, 512, 0, stream>>>(qbf, kbf, vtr, y);
}